// Round 11
// baseline (182.381 us; speedup 1.0000x reference)
//
#include <hip/hip_runtime.h>

typedef __fp16 h2 __attribute__((ext_vector_type(2)));

constexpr int VIEWS = 360;
constexpr int IMGSZ = 512;
constexpr int WCHUNK = 64;   // w per block
constexpr int KH = 64;       // h per LDS chunk
constexpr int NXF4 = 25;     // staged box width in 4-dword groups (100 texels)
constexpr int PITCH = 100;   // dwords per LDS row (R0-validated)
constexpr int MAXNY = 94;    // max staged rows
constexpr int LDSDW = PITCH * MAXNY;   // 9400 dwords
constexpr int PW = 712;      // padded width (dword positions per row)
constexpr int PH = 704;      // padded height
constexpr int PAD = 96;
// Safe byte-address clamp for speculative tail reads (room for +PITCH+1 dw)
constexpr unsigned MAXA = (unsigned)(LDSDW - PITCH - 2) * 4u;

// ---------- pad kernel: zero-padded, BATCH-PACKED f16 texels ---------------
__global__ __launch_bounds__(256) void pad_kernel(const float* __restrict__ x,
                                                  unsigned* __restrict__ padq) {
    constexpr int PW4 = PW / 4;              // 178 groups per row
    constexpr int total = PH * PW4;          // 125312 groups
    int idx = blockIdx.x * 256 + threadIdx.x;
    if (idx >= total) return;
    int py = idx / PW4;
    int px4 = idx - py * PW4;
    int gx = px4 * 4 - PAD;                  // multiple of 4
    int gy = py - PAD;
    const float* img0 = x;
    const float* img1 = x + (size_t)IMGSZ * IMGSZ;
    float4 a = make_float4(0.f, 0.f, 0.f, 0.f);
    float4 bq = a;
    if ((unsigned)gy < (unsigned)IMGSZ && (unsigned)gx < (unsigned)IMGSZ) {
        size_t off = (size_t)gy * IMGSZ + gx;    // gx%4==0 -> all-in/all-out
        a  = *(const float4*)(img0 + off);
        bq = *(const float4*)(img1 + off);
    }
    uint4 d;
    d.x = __builtin_bit_cast(unsigned, __builtin_amdgcn_cvt_pkrtz(a.x, bq.x));
    d.y = __builtin_bit_cast(unsigned, __builtin_amdgcn_cvt_pkrtz(a.y, bq.y));
    d.z = __builtin_bit_cast(unsigned, __builtin_amdgcn_cvt_pkrtz(a.z, bq.z));
    d.w = __builtin_bit_cast(unsigned, __builtin_amdgcn_cvt_pkrtz(a.w, bq.w));
    *(uint4*)&padq[(size_t)idx * 4] = d;
}

// Fire-and-forget f32 atomic, NO memory clobber (out[] is never read here;
// LDS scheduling must not be fenced by it -- R9's clobber serialized the loop).
__device__ __forceinline__ void gatomic_fadd(float* p, float v) {
    asm volatile("global_atomic_add_f32 %0, %1, off" : : "v"(p), "v"(v));
}

// One DPP accumulate step with a LITERAL ctrl (builtin requires constant).
template <int CTRL>
__device__ __forceinline__ h2 dpp_add_step(h2 acc) {
    int t = __builtin_amdgcn_update_dpp(
        0, (int)__builtin_bit_cast(unsigned, acc), CTRL, 0xf, 0xf, true);
    return acc + __builtin_bit_cast(h2, (unsigned)t);
}

// 16-lane group reduce: lane 16q+15 holds the sum of its group.
__device__ __forceinline__ h2 dpp_group_reduce(h2 x) {
    x = dpp_add_step<0x111>(x);   // row_shr:1
    x = dpp_add_step<0x112>(x);   // row_shr:2
    x = dpp_add_step<0x114>(x);   // row_shr:4
    x = dpp_add_step<0x118>(x);   // row_shr:8
    return x;
}

// ---------- main kernel: paired views, off-loop column reduction -----------
// Identity (validated R9): sample_{v+180}(h, w) = sample_v(511-w, h).
// Row view v: per-lane sum over h. Column view v+180: per-h sum over lanes,
// accumulated in colA[16] registers, reduced once per chunk.
__global__ __launch_bounds__(256, 4) void fp_kernel(const unsigned* __restrict__ padq,
                                                    float* __restrict__ out) {
    __shared__ __align__(16) unsigned tileU[LDSDW];
    __shared__ __align__(16) unsigned colLds[4 * 16 * 4];   // [wave][t][grp]

    int blk = blockIdx.x;          // 1440 = (VIEWS/2) * 8
    int wc = blk & 7;
    int v = blk >> 3;              // row view 0..179
    int vj = v + 180;              // paired column view

    int tid = threadIdx.x;
    int lane = tid & 63;
    int g = tid >> 6;              // h phase 0..3
    int w = wc * WCHUNK + lane;

    double ang = -3.14159265358979323846 * (double)(v + 1) / (double)VIEWS
                 - 3.14159265358979323846;
    float c = (float)cos(ang);
    float s = (float)sin(ang);

    float xw = (float)w + 0.5f - 256.0f;
    float cxw = fmaf(c, xw, 255.5f);
    float sxw = fmaf(s, xw, 255.5f);

    // Per-thread valid-h interval (validated rounds 0-9).
    float lo = -1e30f, hi = 1e30f;
    {
        float coef = -s, base = cxw;
        if (fabsf(coef) > 1e-6f) {
            float a = (-1.0f - base) / coef;
            float bq = (512.0f - base) / coef;
            lo = fmaxf(lo, fminf(a, bq));
            hi = fminf(hi, fmaxf(a, bq));
        } else if (!(base > -1.0f && base < 512.0f)) {
            lo = 1e30f; hi = -1e30f;
        }
    }
    {
        float coef = c, base = sxw;
        if (fabsf(coef) > 1e-6f) {
            float a = (-1.0f - base) / coef;
            float bq = (512.0f - base) / coef;
            lo = fmaxf(lo, fminf(a, bq));
            hi = fminf(hi, fmaxf(a, bq));
        } else if (!(base > -1.0f && base < 512.0f)) {
            lo = 1e30f; hi = -1e30f;
        }
    }
    float h0f = fminf(fmaxf(floorf(lo + 255.5f) - 1.0f, 0.0f), 512.0f);
    float h1f = fminf(fmaxf(ceilf(hi + 255.5f) + 1.0f, -1.0f), 511.0f);
    int h0 = (int)h0f;
    int h1 = (int)h1f;

    int bh0 = h0, bh1 = h1;
    #pragma unroll
    for (int m = 1; m < 64; m <<= 1) {
        bh0 = min(bh0, __shfl_xor(bh0, m, 64));
        bh1 = max(bh1, __shfl_xor(bh1, m, 64));
    }

    float xa = (float)(wc * WCHUNK) + 0.5f - 256.0f;
    float xb = xa + 63.0f;

    float acc0 = 0.0f, acc1 = 0.0f;
    float step4x = -4.0f * s;
    float step4y = 4.0f * c;

    for (int hc = bh0; hc <= bh1; hc += KH) {
        int hend = min(hc + KH - 1, bh1);

        float ha = (float)hc - 255.5f;
        float hb = (float)hend - 255.5f;
        float ix00 = c * xa - s * ha, ix01 = c * xa - s * hb;
        float ix10 = c * xb - s * ha, ix11 = c * xb - s * hb;
        float iy00 = s * xa + c * ha, iy01 = s * xa + c * hb;
        float iy10 = s * xb + c * ha, iy11 = s * xb + c * hb;
        float ixmn = fminf(fminf(ix00, ix01), fminf(ix10, ix11)) + 255.5f;
        float iymn = fminf(fminf(iy00, iy01), fminf(iy10, iy11)) + 255.5f;
        float iymx = fmaxf(fmaxf(iy00, iy01), fmaxf(iy10, iy11)) + 255.5f;
        int x_lo = (int)floorf(ixmn) - 1;
        int x_lo4 = x_lo & ~3;
        int y_lo = (int)floorf(iymn) - 1;
        int NY = min((int)floorf(iymx) + 3 - y_lo, MAXNY);
        int total4 = NY * NXF4;            // <= 2350
        int nit = (total4 + 255) >> 8;     // <= 10

        __syncthreads();

        // R0-validated staging: coalesced b128, clamped duplicates benign.
        {
            const unsigned* pb = padq + (y_lo + PAD) * PW + (x_lo4 + PAD);
            for (int k = 0; k < nit; ++k) {
                int ic = min((k << 8) + tid, total4 - 1);
                int ry = ic / NXF4;                    // const magic-mul
                uint4 val = *(const uint4*)(pb + 4 * ic + (PW - 4 * NXF4) * ry);
                *(uint4*)&tileU[ic << 2] = val;
            }
        }
        __syncthreads();

        // Gather: fully unrolled 16 trips (full chunks have exactly 16);
        // wave-uniform guard zeroes the tail; clamped addr -> safe reads.
        float hh0 = (float)(hc + g) - 255.5f;
        float ixr = fmaf(-s, hh0, cxw) - (float)x_lo4;
        float iyr = fmaf(c, hh0, sxw) - (float)y_lo;
        h2 accp0 = (h2)0.0f;
        h2 accp1 = (h2)0.0f;
        h2 colA[16];
        #pragma unroll
        for (int t = 0; t < 16; ++t) colA[t] = (h2)0.0f;
        #pragma unroll
        for (int t = 0; t < 16; ++t) {
            float tx = truncf(ixr);
            float ty = truncf(iyr);
            float wx1 = ixr - tx;
            float wy1 = iyr - ty;
            h2 wxs = __builtin_amdgcn_cvt_pkrtz(wx1, wx1);
            h2 wys = __builtin_amdgcn_cvt_pkrtz(wy1, wy1);
            unsigned a = (unsigned)fmaf(ty, 400.0f, tx * 4.0f);
            a = min(a, MAXA);
            const unsigned* p = (const unsigned*)((const char*)tileU + a);
            h2 t00 = __builtin_bit_cast(h2, p[0]);
            h2 t01 = __builtin_bit_cast(h2, p[1]);
            h2 t10 = __builtin_bit_cast(h2, p[PITCH]);
            h2 t11 = __builtin_bit_cast(h2, p[PITCH + 1]);
            h2 r0 = t00 + (t01 - t00) * wxs;
            h2 r1 = t10 + (t11 - t10) * wxs;
            h2 contrib = r0 + (r1 - r0) * wys;
            if (hc + g + 4 * t <= hend) {          // wave-uniform
                if (t & 1) accp1 += contrib; else accp0 += contrib;
                colA[t] = contrib;
            }
            ixr += step4x;
            iyr += step4y;
        }
        acc0 += (float)accp0.x + (float)accp1.x;
        acc1 += (float)accp0.y + (float)accp1.y;

        // Column reduction, off the load path: 16 independent 4-step DPP
        // group-reduces (lane 16q+15 holds sum of its 16-lane group).
        #pragma unroll
        for (int t = 0; t < 16; ++t) colA[t] = dpp_group_reduce(colA[t]);

        // Transpose 4 group-partials per t through tiny LDS (wave-local).
        {
            unsigned* cl = colLds + (g << 6);
            int grp = lane >> 4;
            if ((lane & 15) == 15) {
                #pragma unroll
                for (int t = 0; t < 16; ++t)
                    cl[(t << 2) + grp] = __builtin_bit_cast(unsigned, colA[t]);
            }
            int h = hc + g + 4 * lane;             // lane plays t here
            if (lane < 16 && h <= hend) {
                uint4 q = *(const uint4*)&cl[lane << 2];
                h2 sA = __builtin_bit_cast(h2, q.x) + __builtin_bit_cast(h2, q.y);
                h2 sB = __builtin_bit_cast(h2, q.z) + __builtin_bit_cast(h2, q.w);
                h2 red = sA + sB;
                if (__builtin_bit_cast(unsigned, red) != 0u) {
                    float* p0 = out + ((size_t)(511 - h) * VIEWS + vj);
                    gatomic_fadd(p0, (float)red.x * 0.5f);
                    gatomic_fadd(p0 + (size_t)IMGSZ * VIEWS, (float)red.y * 0.5f);
                }
            }
        }
    }

    // Reduce the 4 h-phase partials for view v (both batches), reusing tile.
    __syncthreads();
    tileU[(g << 6) + lane] = __float_as_uint(acc0);
    tileU[256 + (g << 6) + lane] = __float_as_uint(acc1);
    __syncthreads();
    if (g == 0) {
        float r0 = __uint_as_float(tileU[lane]) + __uint_as_float(tileU[64 + lane]) +
                   __uint_as_float(tileU[128 + lane]) + __uint_as_float(tileU[192 + lane]);
        float r1 = __uint_as_float(tileU[256 + lane]) + __uint_as_float(tileU[320 + lane]) +
                   __uint_as_float(tileU[384 + lane]) + __uint_as_float(tileU[448 + lane]);
        size_t o = (size_t)w * VIEWS + v;
        out[o] = r0 * 0.5f;
        out[(size_t)IMGSZ * VIEWS + o] = r1 * 0.5f;
    }
}

extern "C" void kernel_launch(void* const* d_in, const int* in_sizes, int n_in,
                              void* d_out, int out_size, void* d_ws, size_t ws_size,
                              hipStream_t stream) {
    const float* x = (const float*)d_in[0];
    float* out = (float*)d_out;
    unsigned* padq = (unsigned*)d_ws;   // PH*PW*4 = 2,004,992 bytes

    constexpr int padTotal = PH * (PW / 4);          // 125312 groups
    pad_kernel<<<(padTotal + 255) / 256, 256, 0, stream>>>(x, padq);

    int nblocks = (VIEWS / 2) * (IMGSZ / WCHUNK);    // 1440
    fp_kernel<<<nblocks, 256, 0, stream>>>(padq, out);
}

// Round 12
// 178.638 us; speedup vs baseline: 1.0210x; 1.0210x over previous
//
#include <hip/hip_runtime.h>

typedef __fp16 h2 __attribute__((ext_vector_type(2)));

constexpr int VIEWS = 360;
constexpr int IMGSZ = 512;
constexpr int WCHUNK = 64;   // w per block
constexpr int KH = 40;       // h per chunk (smaller tile -> two LDS buffers fit)
constexpr int PITCH = 84;    // dwords per LDS row (width bound 81 at KH=40)
constexpr int NXF4 = 21;     // 16B groups per row
constexpr int MAXNY = 79;    // rows bound: ceil(sqrt(63^2+39^2))+4 (R4-validated)
constexpr int TDW = PITCH * MAXNY;   // 6636 dw = 26544 B per buffer
constexpr int PW = 712;      // padded width (dwords per row)
constexpr int PH = 704;      // padded height
constexpr int PAD = 96;
constexpr int NT = 512;      // 8 waves/block; 3 blocks/CU -> 24 waves/CU

// Async global->LDS 16B copy (R1-validated). LDS dest = uniform base+lane*16.
#define ASYNC_CP16(SRC, DST)                                              \
    __builtin_amdgcn_global_load_lds(                                     \
        (const __attribute__((address_space(1))) unsigned*)(SRC),         \
        (__attribute__((address_space(3))) unsigned*)(DST), 16, 0, 0)

// ---------- pad kernel: zero-padded, BATCH-PACKED f16 texels ---------------
__global__ __launch_bounds__(256) void pad_kernel(const float* __restrict__ x,
                                                  unsigned* __restrict__ padq) {
    constexpr int PW4 = PW / 4;              // 178 groups per row
    constexpr int total = PH * PW4;          // 125312 groups
    int idx = blockIdx.x * 256 + threadIdx.x;
    if (idx >= total) return;
    int py = idx / PW4;
    int px4 = idx - py * PW4;
    int gx = px4 * 4 - PAD;                  // multiple of 4
    int gy = py - PAD;
    const float* img0 = x;
    const float* img1 = x + (size_t)IMGSZ * IMGSZ;
    float4 a = make_float4(0.f, 0.f, 0.f, 0.f);
    float4 bq = a;
    if ((unsigned)gy < (unsigned)IMGSZ && (unsigned)gx < (unsigned)IMGSZ) {
        size_t off = (size_t)gy * IMGSZ + gx;    // gx%4==0 -> all-in/all-out
        a  = *(const float4*)(img0 + off);
        bq = *(const float4*)(img1 + off);
    }
    uint4 d;
    d.x = __builtin_bit_cast(unsigned, __builtin_amdgcn_cvt_pkrtz(a.x, bq.x));
    d.y = __builtin_bit_cast(unsigned, __builtin_amdgcn_cvt_pkrtz(a.y, bq.y));
    d.z = __builtin_bit_cast(unsigned, __builtin_amdgcn_cvt_pkrtz(a.z, bq.z));
    d.w = __builtin_bit_cast(unsigned, __builtin_amdgcn_cvt_pkrtz(a.w, bq.w));
    *(uint4*)&padq[(size_t)idx * 4] = d;
}

// ---------- main kernel: double-buffered chunks, 1 barrier per chunk -------
__global__ __launch_bounds__(NT, 4) void fp_kernel(const unsigned* __restrict__ padq,
                                                   float* __restrict__ out) {
    // Two STATICALLY NAMED buffers: alias analysis keeps the prefetch's
    // global_load_lds (to one) from fencing the ds_reads (from the other).
    __shared__ __align__(16) unsigned bufA[TDW];
    __shared__ __align__(16) unsigned bufB[TDW];

    int blk = blockIdx.x;          // 2880 = VIEWS * 8
    int wc = blk & 7;
    int v = blk >> 3;

    int tid = threadIdx.x;
    int lane = tid & 63;
    int p = tid >> 6;              // h phase 0..7
    int w = wc * WCHUNK + lane;

    double ang = -3.14159265358979323846 * (double)(v + 1) / (double)VIEWS
                 - 3.14159265358979323846;
    float c = (float)cos(ang);
    float s = (float)sin(ang);

    float xw = (float)w + 0.5f - 256.0f;
    float cxw = fmaf(c, xw, 255.5f);
    float sxw = fmaf(s, xw, 255.5f);

    // Per-thread valid-h interval (validated rounds 0-11).
    float lo = -1e30f, hi = 1e30f;
    {
        float coef = -s, base = cxw;
        if (fabsf(coef) > 1e-6f) {
            float a = (-1.0f - base) / coef;
            float bq = (512.0f - base) / coef;
            lo = fmaxf(lo, fminf(a, bq));
            hi = fminf(hi, fmaxf(a, bq));
        } else if (!(base > -1.0f && base < 512.0f)) {
            lo = 1e30f; hi = -1e30f;
        }
    }
    {
        float coef = c, base = sxw;
        if (fabsf(coef) > 1e-6f) {
            float a = (-1.0f - base) / coef;
            float bq = (512.0f - base) / coef;
            lo = fmaxf(lo, fminf(a, bq));
            hi = fminf(hi, fmaxf(a, bq));
        } else if (!(base > -1.0f && base < 512.0f)) {
            lo = 1e30f; hi = -1e30f;
        }
    }
    float h0f = fminf(fmaxf(floorf(lo + 255.5f) - 1.0f, 0.0f), 512.0f);
    float h1f = fminf(fmaxf(ceilf(hi + 255.5f) + 1.0f, -1.0f), 511.0f);
    int h0 = (int)h0f;
    int h1 = (int)h1f;

    // Wave union; identical lane->w map in all 8 waves -> same result.
    int bh0 = h0, bh1 = h1;
    #pragma unroll
    for (int m = 1; m < 64; m <<= 1) {
        bh0 = min(bh0, __shfl_xor(bh0, m, 64));
        bh1 = max(bh1, __shfl_xor(bh1, m, 64));
    }

    float xa = (float)(wc * WCHUNK) + 0.5f - 256.0f;
    float xb = xa + 63.0f;

    float acc0 = 0.0f, acc1 = 0.0f;
    float step8x = -8.0f * s;
    float step8y = 8.0f * c;

// bbox for chunk starting at HC -> X4 (x_lo4), YL (y_lo), T4, NIT
#define BBOX(HC, X4, YL, T4, NIT)                                           \
    {                                                                       \
        int hend_ = min((HC) + KH - 1, bh1);                                \
        float ha_ = (float)(HC) - 255.5f;                                   \
        float hb_ = (float)hend_ - 255.5f;                                  \
        float sha_ = s * ha_, shb_ = s * hb_;                               \
        float cha_ = c * ha_, chb_ = c * hb_;                               \
        float cxa_ = c * xa, cxb_ = c * xb;                                 \
        float sxa_ = s * xa, sxb_ = s * xb;                                 \
        float ixmn_ = fminf(cxa_, cxb_) - fmaxf(sha_, shb_) + 255.5f;       \
        float iymn_ = fminf(sxa_, sxb_) + fminf(cha_, chb_) + 255.5f;       \
        float iymx_ = fmaxf(sxa_, sxb_) + fmaxf(cha_, chb_) + 255.5f;       \
        X4 = ((int)floorf(ixmn_) - 1) & ~3;                                 \
        YL = (int)floorf(iymn_) - 1;                                        \
        int NY_ = min((int)floorf(iymx_) + 3 - (YL), MAXNY);                \
        T4 = NY_ * NXF4;                                                    \
        NIT = ((T4) + NT - 1) >> 9;                                         \
    }

// issue async staging of chunk (X4,YL,T4,NIT) into BUF (no waits here)
#define STAGE(BUF, X4, YL, T4, NIT)                                         \
    {                                                                       \
        const unsigned* pb_ = padq + ((YL) + PAD) * PW + ((X4) + PAD);      \
        for (int k_ = 0; k_ < (NIT); ++k_) {                                \
            int i_ = (k_ << 9) + tid;                                       \
            if (((k_ << 9) + (p << 6) + 63) < (T4)) {                       \
                int ry_ = (i_ * 6242) >> 17;              /* i/21 */        \
                ASYNC_CP16(pb_ + 4 * i_ + (PW - 4 * NXF4) * ry_,            \
                           &BUF[i_ << 2]);                                  \
            } else if (i_ < (T4)) {                                         \
                int ry_ = (i_ * 6242) >> 17;                                \
                uint4 val_ = *(const uint4*)(pb_ + 4 * i_ +                 \
                                             (PW - 4 * NXF4) * ry_);        \
                *(uint4*)&BUF[i_ << 2] = val_;                              \
            }                                                               \
        }                                                                   \
    }

// gather chunk HC from BUF using its (X4,YL); wave p takes h = HC+p, +8, ...
#define GATHER(BUF, HC, X4, YL)                                             \
    {                                                                       \
        int hend_ = min((HC) + KH - 1, bh1);                                \
        float hh0_ = (float)((HC) + p) - 255.5f;                            \
        float ixr_ = fmaf(-s, hh0_, cxw) - (float)(X4);                     \
        float iyr_ = fmaf(c, hh0_, sxw) - (float)(YL);                      \
        h2 a0_ = (h2)0.0f, a1_ = (h2)0.0f;                                  \
        int par_ = 0;                                                       \
        _Pragma("unroll 5")                                                 \
        for (int h_ = (HC) + p; h_ <= hend_; h_ += 8) {                     \
            float tx_ = truncf(ixr_);                                       \
            float ty_ = truncf(iyr_);                                       \
            float wx_ = ixr_ - tx_;                                         \
            float wy_ = iyr_ - ty_;                                         \
            h2 wxs_ = __builtin_amdgcn_cvt_pkrtz(wx_, wx_);                 \
            h2 wys_ = __builtin_amdgcn_cvt_pkrtz(wy_, wy_);                 \
            unsigned a_ = (unsigned)fmaf(ty_, 336.0f, tx_ * 4.0f);          \
            const unsigned* pt_ =                                           \
                (const unsigned*)((const char*)BUF + a_);                   \
            h2 t00_ = __builtin_bit_cast(h2, pt_[0]);                       \
            h2 t01_ = __builtin_bit_cast(h2, pt_[1]);                       \
            h2 t10_ = __builtin_bit_cast(h2, pt_[PITCH]);                   \
            h2 t11_ = __builtin_bit_cast(h2, pt_[PITCH + 1]);               \
            h2 r0_ = t00_ + (t01_ - t00_) * wxs_;                           \
            h2 r1_ = t10_ + (t11_ - t10_) * wxs_;                           \
            h2 ct_ = r0_ + (r1_ - r0_) * wys_;                              \
            if (par_) a1_ += ct_; else a0_ += ct_;                          \
            par_ ^= 1;                                                      \
            ixr_ += step8x;                                                 \
            iyr_ += step8y;                                                 \
        }                                                                   \
        acc0 += (float)a0_.x + (float)a1_.x;                                \
        acc1 += (float)a0_.y + (float)a1_.y;                                \
    }

    if (bh0 <= bh1) {
        int x4_0, yl_0, t4_0, nit_0;
        int x4_1, yl_1, t4_1, nit_1;

        // Prologue: stage chunk 0 into bufA.
        BBOX(bh0, x4_0, yl_0, t4_0, nit_0);
        STAGE(bufA, x4_0, yl_0, t4_0, nit_0);
        __syncthreads();                       // compiler drains vmcnt here

        for (int hc = bh0; hc <= bh1; hc += 2 * KH) {
            int hc1 = hc + KH;
            // Prefetch chunk hc+KH into bufB while gathering hc from bufA.
            if (hc1 <= bh1) {
                BBOX(hc1, x4_1, yl_1, t4_1, nit_1);
                STAGE(bufB, x4_1, yl_1, t4_1, nit_1);
            }
            GATHER(bufA, hc, x4_0, yl_0);
            __syncthreads();                   // bufB ready; bufA free

            if (hc1 <= bh1) {
                int hc2 = hc + 2 * KH;
                // Prefetch hc+2KH into bufA while gathering hc+KH from bufB.
                if (hc2 <= bh1) {
                    BBOX(hc2, x4_0, yl_0, t4_0, nit_0);
                    STAGE(bufA, x4_0, yl_0, t4_0, nit_0);
                }
                GATHER(bufB, hc1, x4_1, yl_1);
                __syncthreads();               // bufA ready; bufB free
            }
        }
    }

    // Reduce the 8 phase partials for both batches, reusing bufA.
    __syncthreads();
    bufA[(p << 6) + lane] = __float_as_uint(acc0);
    bufA[512 + (p << 6) + lane] = __float_as_uint(acc1);
    __syncthreads();
    if (p < 2) {                 // wave 0 -> batch 0, wave 1 -> batch 1
        const unsigned* base = bufA + (p << 9);
        float r = 0.0f;
        #pragma unroll
        for (int q = 0; q < 8; ++q) r += __uint_as_float(base[(q << 6) + lane]);
        size_t o = (size_t)w * VIEWS + v;
        out[o + (size_t)p * IMGSZ * VIEWS] = r * 0.5f;
    }
}

extern "C" void kernel_launch(void* const* d_in, const int* in_sizes, int n_in,
                              void* d_out, int out_size, void* d_ws, size_t ws_size,
                              hipStream_t stream) {
    const float* x = (const float*)d_in[0];
    float* out = (float*)d_out;
    unsigned* padq = (unsigned*)d_ws;   // PH*PW*4 = 2,004,992 bytes

    constexpr int padTotal = PH * (PW / 4);          // 125312 groups
    pad_kernel<<<(padTotal + 255) / 256, 256, 0, stream>>>(x, padq);

    int nblocks = VIEWS * (IMGSZ / WCHUNK);          // 2880
    fp_kernel<<<nblocks, NT, 0, stream>>>(padq, out);
}